// Round 13
// baseline (189.581 us; speedup 1.0000x reference)
//
#include <hip/hip_runtime.h>

typedef _Float16 f16;
typedef _Float16 half8 __attribute__((ext_vector_type(8)));
typedef _Float16 half4v __attribute__((ext_vector_type(4)));
typedef float floatx4 __attribute__((ext_vector_type(4)));

#define B_ 64
#define T_ 256
#define C_ 384
#define H_ 6
#define D_ 64
#define NROWS (B_*T_)

typedef __attribute__((address_space(3))) void lds_void_t;
typedef const __attribute__((address_space(1))) void gvoid_t;

__device__ __forceinline__ void g2lds16(const void* g, void* l) {
  __builtin_amdgcn_global_load_lds((gvoid_t*)g, (lds_void_t*)l, 16, 0, 0);
}

// ---------------- prep: weight repack fp32->f16 FRAGMENT-MAJOR + biases ----------------
// R10-proven:
//   element (col, k) -> W[((k>>5)*NCT + (col>>4))*512 + (((k>>3)&3)*16 + (col&15))*8 + (k&7)]
// Wqkv: NCT=72 (col = mat*384 + h*64 + d); Wp/W1/W2: NCT=24.
__global__ __launch_bounds__(256) void prep_kernel(
    const float* __restrict__ Wq, const float* __restrict__ Wk, const float* __restrict__ Wv,
    const float* __restrict__ bq, const float* __restrict__ bk, const float* __restrict__ bv,
    const float* __restrict__ Wp, const float* __restrict__ W1, const float* __restrict__ W2,
    f16* __restrict__ Wqkv_t, f16* __restrict__ Wp_t, f16* __restrict__ W1_t, f16* __restrict__ W2_t,
    float* __restrict__ bqkv)
{
  const int bid = blockIdx.x;
  const int tid = threadIdx.x;
  if (bid == 216) {
    for (int i = tid; i < 1152; i += 256) {
      float v;
      if (i < 384)      v = bq[i];
      else if (i < 768) v = bk[i - 384];
      else              v = bv[i - 768];
      bqkv[i] = v;
    }
    return;
  }
  __shared__ __align__(16) float tile[64*68];
  const float* src; int srcStride; f16* O; int ctile_base, nct, ks_base;
  if (bid < 108) {
    int mat = bid / 36, rem = bid - mat*36;
    int h = rem / 6, kt = rem - h*6;
    const float* W = (mat == 0) ? Wq : (mat == 1) ? Wk : Wv;
    src = W + (size_t)(h*384 + kt*64)*64;   // rows k (64), cols d (64)
    srcStride = 64;
    O = Wqkv_t; ctile_base = mat*24 + h*4; nct = 72; ks_base = kt*2;
  } else {
    int b2 = bid - 108;
    int mat = b2 / 36, rem = b2 - mat*36;
    int kt = rem / 6, ct = rem - kt*6;
    const float* W = (mat == 0) ? Wp : (mat == 1) ? W1 : W2;
    src = W + (size_t)(kt*64)*384 + ct*64;  // rows k (64), cols d (64)
    srcStride = 384;
    O = (mat == 0) ? Wp_t : (mat == 1) ? W1_t : W2_t;
    ctile_base = ct*4; nct = 24; ks_base = kt*2;
  }
#pragma unroll
  for (int i = 0; i < 4; i++) {
    int idx = i*256 + tid;
    int r = idx >> 4, c4 = idx & 15;
    float4 v = *(const float4*)(src + (size_t)r*srcStride + c4*4);
    *(float4*)(&tile[r*68 + c4*4]) = v;
  }
  __syncthreads();
#pragma unroll
  for (int i = 0; i < 4; i++) {
    int idx = i*256 + tid;
    int d = idx >> 4, k4 = idx & 15;     // d: col within tile; k = k4*4+j
    half4v o;
#pragma unroll
    for (int j = 0; j < 4; j++) o[j] = (f16)tile[(k4*4 + j)*68 + d];
    int ks    = ks_base + (k4 >> 3);
    int ctile = ctile_base + (d >> 4);
    int slotq = (k4 >> 1) & 3;
    size_t off = (size_t)(ks*nct + ctile)*512 + (size_t)(slotq*16 + (d & 15))*8 + (k4 & 1)*4;
    *(half4v*)(O + off) = o;
  }
}

// ---------------- fused LN1 + QKV GEMM (R11-proven) ----------------
__global__ __launch_bounds__(512, 2) void qkv_ln_kernel(
    const float* __restrict__ x, const float* __restrict__ gamma, const float* __restrict__ beta,
    const f16* __restrict__ WR, const float* __restrict__ bias, f16* __restrict__ qkv)
{
  __shared__ __align__(16) f16 rowbuf[12*64*32];   // 49152B: h (LN1 output)
  __shared__ float lnred[2][64][4];
  __shared__ float lnmv[2][64];

  const int tid = threadIdx.x;
  const int lane = tid & 63, w = tid >> 6;
  const int wm = w >> 2, wn = w & 3;
  const int q = lane >> 4, c15 = lane & 15;
  const long row0 = (long)blockIdx.x * 64;
  const int chf = blockIdx.y;          // column half: 0 or 1

  // ---- LN1 over x (full 384 input cols; wn indexes INPUT col-quarters)
  float cg[6], cb[6];
#pragma unroll
  for (int ni = 0; ni < 6; ni++) {
    int col = wn*96 + ni*16 + c15;
    cg[ni] = gamma[col]; cb[ni] = beta[col];
  }
  float xv[2][6][4];
#pragma unroll
  for (int mi = 0; mi < 2; mi++)
#pragma unroll
    for (int rr = 0; rr < 4; rr++) {
      long row = row0 + wm*32 + mi*16 + q*4 + rr;
#pragma unroll
      for (int ni = 0; ni < 6; ni++)
        xv[mi][ni][rr] = x[row*384 + wn*96 + ni*16 + c15];
    }
#pragma unroll
  for (int mi = 0; mi < 2; mi++) {
#pragma unroll
    for (int rr = 0; rr < 4; rr++) {
      float s = 0.f, s2 = 0.f;
#pragma unroll
      for (int ni = 0; ni < 6; ni++) { float v = xv[mi][ni][rr]; s += v; s2 += v*v; }
      s  += __shfl_xor(s, 1);  s  += __shfl_xor(s, 2);  s  += __shfl_xor(s, 4);  s  += __shfl_xor(s, 8);
      s2 += __shfl_xor(s2, 1); s2 += __shfl_xor(s2, 2); s2 += __shfl_xor(s2, 4); s2 += __shfl_xor(s2, 8);
      if (c15 == 0) {
        int lr = wm*32 + mi*16 + q*4 + rr;
        lnred[0][lr][wn] = s;
        lnred[1][lr][wn] = s2;
      }
    }
  }
  __syncthreads();
  if (tid < 64) {
    float s = 0.f, s2 = 0.f;
#pragma unroll
    for (int j = 0; j < 4; j++) { s += lnred[0][tid][j]; s2 += lnred[1][tid][j]; }
    float mu = s * (1.f/384.f);
    float var = s2 * (1.f/384.f) - mu*mu;
    lnmv[0][tid] = mu;
    lnmv[1][tid] = rsqrtf(var + 1e-5f);
  }
  __syncthreads();
  // h -> rowbuf (staged-A swizzled layout; R8/R9-proven write/read pair)
#pragma unroll
  for (int mi = 0; mi < 2; mi++) {
#pragma unroll
    for (int rr = 0; rr < 4; rr++) {
      int lr = wm*32 + mi*16 + q*4 + rr;
      float mu = lnmv[0][lr], rs = lnmv[1][lr];
      int s_ = (lr >> 1) & 3;
#pragma unroll
      for (int ni = 0; ni < 6; ni++) {
        int cc = wn*96 + ni*16 + c15;
        float hv = (xv[mi][ni][rr] - mu)*rs*cg[ni] + cb[ni];
        int chunk = cc >> 5, kk2 = cc & 31;
        int pos = ((kk2 >> 3) ^ s_)*8 + (kk2 & 7);
        rowbuf[chunk*2048 + lr*32 + pos] = (f16)hv;
      }
    }
  }
  __syncthreads();   // h published -- last barrier in the kernel

  // ---- barrier-free GEMM: this block's 576-col half (wn indexes OUTPUT cols)
  floatx4 acc[2][9] = {};
#pragma unroll
  for (int kg = 0; kg < 12; kg++) {
    half8 af[2];
#pragma unroll
    for (int mi = 0; mi < 2; mi++) {
      int r = wm*32 + mi*16 + c15;
      int ph = q ^ ((r >> 1) & 3);
      af[mi] = *(const half8*)(&rowbuf[kg*2048 + r*32 + ph*8]);
    }
#pragma unroll
    for (int g3 = 0; g3 < 3; g3++) {
      half8 bf[3];
#pragma unroll
      for (int ni = 0; ni < 3; ni++)
        bf[ni] = *(const half8*)(WR + (size_t)(kg*72 + chf*36 + wn*9 + g3*3 + ni)*512 + lane*8);
#pragma unroll
      for (int mi = 0; mi < 2; mi++)
#pragma unroll
        for (int ni = 0; ni < 3; ni++)
          acc[mi][g3*3 + ni] = __builtin_amdgcn_mfma_f32_16x16x32_f16(af[mi], bf[ni], acc[mi][g3*3 + ni], 0, 0, 0);
    }
  }

  // ---- epilogue: + bias, f16 out
  float bb[9];
#pragma unroll
  for (int ni = 0; ni < 9; ni++) bb[ni] = bias[chf*576 + wn*144 + ni*16 + c15];
#pragma unroll
  for (int mi = 0; mi < 2; mi++) {
#pragma unroll
    for (int rr = 0; rr < 4; rr++) {
      long row = row0 + wm*32 + mi*16 + q*4 + rr;
#pragma unroll
      for (int ni = 0; ni < 9; ni++) {
        long col = chf*576 + wn*144 + ni*16 + c15;
        qkv[row*1152 + col] = (f16)(acc[mi][ni][rr] + bb[ni]);
      }
    }
  }
}

// ---------------- fused causal attention (R6-proven) ----------------
__global__ __launch_bounds__(512, 2) void attn_kernel(const f16* __restrict__ qkv,
                                                      f16* __restrict__ attn_out)
{
  __shared__ __align__(16) char kvbuf[32768];
  __shared__ __align__(16) f16 Pbuf[8][16*64];
  f16* Ks = (f16*)kvbuf;
  unsigned int* vTw = (unsigned int*)kvbuf;
  f16* vT = (f16*)kvbuf;

  const int tid = threadIdx.x;
  const int bid = blockIdx.x;
  const int bh = bid >> 1, qt2 = bid & 1;
  const int b = bh / 6, h = bh - b*6;
  const f16* qp = qkv + (size_t)b*256*1152 + h*64;
  const f16* kp = qp + 384;
  const f16* vp = qp + 768;
  const int lane = tid & 63, w = tid >> 6;
  const int q = lane >> 4, c15 = lane & 15;

  {
    const int iters = (qt2 + 1) * 2;
    for (int i = 0; i < iters; i++) {
      int pc = i*512 + tid;
      int rc = pc >> 3, p = pc & 7;
      int c = p ^ (rc & 7);
      g2lds16(kp + (size_t)rc*1152 + c*8, (char*)kvbuf + (size_t)(i*512 + w*64)*16);
    }
  }

  const int nmax = qt2*8 + w;
  const int trow0 = qt2*128 + w*16;
  const f16* qrow = qp + (size_t)(trow0 + c15)*1152 + q*8;
  half8 aq0 = *(const half8*)(qrow);
  half8 aq1 = *(const half8*)(qrow + 32);

  __syncthreads();

  floatx4 sacc[16];
  __builtin_amdgcn_s_setprio(1);
#pragma unroll
  for (int ni = 0; ni < 16; ni++) {
    if (ni <= nmax) {
      int s = ni*16 + c15;
      const f16* kr = Ks + s*64;
      int p0 = q ^ (s & 7);
      half8 b0 = *(const half8*)(kr + p0*8);
      half8 b1 = *(const half8*)(kr + (p0 ^ 4)*8);
      floatx4 a = {0.f, 0.f, 0.f, 0.f};
      a = __builtin_amdgcn_mfma_f32_16x16x32_f16(aq0, b0, a, 0, 0, 0);
      a = __builtin_amdgcn_mfma_f32_16x16x32_f16(aq1, b1, a, 0, 0, 0);
      sacc[ni] = a;
    }
  }
  __builtin_amdgcn_s_setprio(0);
  __syncthreads();

  half8 va[2], vb[2];
#pragma unroll
  for (int i = 0; i < 2; i++) {
    if (i <= qt2) {
      int idx = i*512 + tid;
      int sp = idx >> 3, part = idx & 7;
      const f16* v0 = vp + (size_t)(2*sp)*1152 + part*8;
      va[i] = *(const half8*)(v0);
      vb[i] = *(const half8*)(v0 + 1152);
    }
  }

  const float scale = 0.051031036307982884f;
  float mx[4] = {-1e30f, -1e30f, -1e30f, -1e30f};
#pragma unroll
  for (int ni = 0; ni < 16; ni++) {
    if (ni < nmax) {
#pragma unroll
      for (int r = 0; r < 4; r++) { float v = sacc[ni][r]*scale; sacc[ni][r] = v; mx[r] = fmaxf(mx[r], v); }
    } else if (ni == nmax) {
#pragma unroll
      for (int r = 0; r < 4; r++) {
        float v = sacc[ni][r]*scale;
        v = (c15 <= q*4 + r) ? v : -1e30f;
        sacc[ni][r] = v; mx[r] = fmaxf(mx[r], v);
      }
    }
  }
#pragma unroll
  for (int r = 0; r < 4; r++) {
    mx[r] = fmaxf(mx[r], __shfl_xor(mx[r], 1));
    mx[r] = fmaxf(mx[r], __shfl_xor(mx[r], 2));
    mx[r] = fmaxf(mx[r], __shfl_xor(mx[r], 4));
    mx[r] = fmaxf(mx[r], __shfl_xor(mx[r], 8));
  }
  float l[4] = {0.f, 0.f, 0.f, 0.f};
#pragma unroll
  for (int ni = 0; ni < 16; ni++) {
    if (ni <= nmax) {
#pragma unroll
      for (int r = 0; r < 4; r++) { float p = __expf(sacc[ni][r] - mx[r]); sacc[ni][r] = p; l[r] += p; }
    }
  }
#pragma unroll
  for (int r = 0; r < 4; r++) {
    l[r] += __shfl_xor(l[r], 1);
    l[r] += __shfl_xor(l[r], 2);
    l[r] += __shfl_xor(l[r], 4);
    l[r] += __shfl_xor(l[r], 8);
  }

#pragma unroll
  for (int i = 0; i < 2; i++) {
    if (i <= qt2) {
      int idx = i*512 + tid;
      int sp = idx >> 3, part = idx & 7;
      int csp = sp >> 2, spw = sp & 3;
#pragma unroll
      for (int j = 0; j < 8; j++) {
        int d = part*8 + j;
        int swz = (d & 15) ^ (d >> 3);
        int p = csp ^ swz;
        union { struct { f16 lo, hi; } s; unsigned int u; } pk;
        pk.s.lo = va[i][j]; pk.s.hi = vb[i][j];
        vTw[d*128 + p*4 + spw] = pk.u;
      }
    }
  }
  __syncthreads();

  f16* Pw = &Pbuf[w][0];
  floatx4 oacc[4] = {};
  const int kend_w = (nmax + 1) * 16;
#pragma unroll
  for (int ch = 0; ch < 4; ch++) {
    if (ch*64 < kend_w) {
#pragma unroll
      for (int nl = 0; nl < 4; nl++) {
        int ni = ch*4 + nl;
        if (ni <= nmax) {
#pragma unroll
          for (int r = 0; r < 4; r++) {
            int row = q*4 + r;
            int colp = nl*16 + c15;
            int php = (colp >> 3) ^ (row & 7);
            Pw[row*64 + php*8 + (colp & 7)] = (f16)sacc[ni][r];
          }
        } else if (ni == nmax + 1) {
#pragma unroll
          for (int r = 0; r < 4; r++) {
            int row = q*4 + r;
            int colp = nl*16 + c15;
            int php = (colp >> 3) ^ (row & 7);
            Pw[row*64 + php*8 + (colp & 7)] = (f16)0.f;
          }
        }
      }
      __builtin_amdgcn_s_setprio(1);
#pragma unroll
      for (int kc = 0; kc < 2; kc++) {
        if (ch*64 + kc*32 < kend_w) {
          int pc = (kc*4 + q) ^ (c15 & 7);
          half8 ap = *(const half8*)(Pw + c15*64 + pc*8);
          int sc = ch*8 + kc*4 + q;
#pragma unroll
          for (int nt = 0; nt < 4; nt++) {
            int d = nt*16 + c15;
            int swz = (d & 15) ^ (d >> 3);
            half8 bv = *(const half8*)(vT + d*256 + ((sc ^ swz))*8);
            oacc[nt] = __builtin_amdgcn_mfma_f32_16x16x32_f16(ap, bv, oacc[nt], 0, 0, 0);
          }
        }
      }
      __builtin_amdgcn_s_setprio(0);
    }
  }

  float rl[4];
#pragma unroll
  for (int r = 0; r < 4; r++) rl[r] = 1.0f / l[r];
#pragma unroll
  for (int nt = 0; nt < 4; nt++) {
#pragma unroll
    for (int r = 0; r < 4; r++) {
      int t = trow0 + q*4 + r;
      int d = nt*16 + c15;
      attn_out[(size_t)(b*256 + t)*384 + h*64 + d] = (f16)(oacc[nt][r] * rl[r]);
    }
  }
}

// ---------------- fused tail: proj + residual + LN2 + FF1 + FF2 ----------------
// R13: R12's 32-row/2-blocks-per-CU shape + SOURCE-LEVEL 2-DEEP B PIPELINE.
// R12 counters (VGPR=64, MfmaUtil 12%) showed the compiler compiled the
// K-loop as load->wait->MFMA per kg: 12 serial L2 round-trips per phase.
// Fix: bf[2][6] double-buffer -- prefetch kg+1's fragments BEFORE kg's MFMAs.
// Fully unrolled loop => all indices compile-time (no scratch, rule #20).
// +24 VGPR, converts the chain into a pipelined stream (~1 exposed latency).
__global__ __launch_bounds__(512, 2) void tail_kernel(
    const f16* __restrict__ A, const f16* __restrict__ WpR,
    const f16* __restrict__ W1R, const f16* __restrict__ W2R,
    const float* __restrict__ bp, const float* __restrict__ b1, const float* __restrict__ b2,
    const float* __restrict__ x, const float* __restrict__ g2, const float* __restrict__ be2,
    float* __restrict__ out)
{
  __shared__ __align__(16) f16 rowbuf[12*32*32];   // 24576B: A / h2 / mid
  __shared__ float lnred[2][32][4];
  __shared__ float lnmv[2][32];

  const int tid = threadIdx.x;
  const int lane = tid & 63, w = tid >> 6;
  const int wm = w >> 2, wn = w & 3;     // wm: row half (16 rows), wn: col quarter (96 cols)
  const int q = lane >> 4, c15 = lane & 15;
  const long row0 = (long)blockIdx.x * 32;

  // A staging: 32 rows x 384 cols = 1536 16B-chunks; 3 per thread.
  long offA[3];
#pragma unroll
  for (int i = 0; i < 3; i++) {
    int cb = i*512 + tid;
    int kc = cb >> 7, c2 = cb & 127;
    int rA = c2 >> 2, pA = c2 & 3, gA = pA ^ ((rA >> 1) & 3);
    offA[i] = (row0 + rA)*384 + kc*32 + gA*8;
  }

  floatx4 acc[6] = {};

  // barrier-free GEMM over full K (12 x 32): A from rowbuf, B from L2,
  // bf double-buffered (prefetch kg+1 before MFMA of kg).
#define T_GEMM(WR) do { \
    const f16* wb = (WR) + (size_t)(wn*6)*512 + (size_t)lane*8; \
    half8 bf[2][6]; \
    _Pragma("unroll") \
    for (int ni = 0; ni < 6; ni++) \
      bf[0][ni] = *(const half8*)(wb + (size_t)ni*512); \
    _Pragma("unroll") \
    for (int kg = 0; kg < 12; kg++) { \
      if (kg < 11) { \
        _Pragma("unroll") \
        for (int ni = 0; ni < 6; ni++) \
          bf[(kg+1) & 1][ni] = *(const half8*)(wb + (size_t)((kg+1)*24 + ni)*512); \
      } \
      int r = wm*16 + c15; \
      int ph = q ^ ((r >> 1) & 3); \
      half8 af = *(const half8*)(&rowbuf[kg*1024 + r*32 + ph*8]); \
      _Pragma("unroll") \
      for (int ni = 0; ni < 6; ni++) \
        acc[ni] = __builtin_amdgcn_mfma_f32_16x16x32_f16(af, bf[kg & 1][ni], acc[ni], 0, 0, 0); \
    } \
  } while (0)

  // ---- stage A + prefetch x residual (latency hides under phase a) ----
#pragma unroll
  for (int i = 0; i < 3; i++)
    g2lds16(A + offA[i], (char*)rowbuf + (size_t)(i*512 + w*64)*16);
  float xv[6][4];
#pragma unroll
  for (int rr = 0; rr < 4; rr++) {
    long row = row0 + wm*16 + q*4 + rr;
#pragma unroll
    for (int ni = 0; ni < 6; ni++)
      xv[ni][rr] = x[row*384 + wn*96 + ni*16 + c15];
  }
  __syncthreads();            // [1] A staged

  // ================= phase a: x2 = x + A@Wp + bp ; h2 = LN2(x2) =================
  T_GEMM(WpR);

  float vals[6][4];
  {
    float colb[6], cg[6], cb2[6];
#pragma unroll
    for (int ni = 0; ni < 6; ni++) {
      int col = wn*96 + ni*16 + c15;
      colb[ni] = bp[col]; cg[ni] = g2[col]; cb2[ni] = be2[col];
    }
#pragma unroll
    for (int rr = 0; rr < 4; rr++)
#pragma unroll
      for (int ni = 0; ni < 6; ni++)
        vals[ni][rr] = acc[ni][rr] + colb[ni] + xv[ni][rr];
#pragma unroll
    for (int rr = 0; rr < 4; rr++) {
      float s = 0.f, s2 = 0.f;
#pragma unroll
      for (int ni = 0; ni < 6; ni++) { float v = vals[ni][rr]; s += v; s2 += v*v; }
      s  += __shfl_xor(s, 1);  s  += __shfl_xor(s, 2);  s  += __shfl_xor(s, 4);  s  += __shfl_xor(s, 8);
      s2 += __shfl_xor(s2, 1); s2 += __shfl_xor(s2, 2); s2 += __shfl_xor(s2, 4); s2 += __shfl_xor(s2, 8);
      if (c15 == 0) {
        int lr = wm*16 + q*4 + rr;
        lnred[0][lr][wn] = s;
        lnred[1][lr][wn] = s2;
      }
    }
    __syncthreads();          // [2] lnred ready; all phase-a rowbuf reads done
    if (tid < 32) {
      float s = 0.f, s2 = 0.f;
#pragma unroll
      for (int j = 0; j < 4; j++) { s += lnred[0][tid][j]; s2 += lnred[1][tid][j]; }
      float mu = s * (1.f/384.f);
      float var = s2 * (1.f/384.f) - mu*mu;
      lnmv[0][tid] = mu;
      lnmv[1][tid] = rsqrtf(var + 1e-5f);
    }
    __syncthreads();          // [3] lnmv ready
    // normalize -> h2 into rowbuf (staged-A swizzled layout)
#pragma unroll
    for (int rr = 0; rr < 4; rr++) {
      int lr = wm*16 + q*4 + rr;
      float mu = lnmv[0][lr], rs = lnmv[1][lr];
      int s_ = (lr >> 1) & 3;
#pragma unroll
      for (int ni = 0; ni < 6; ni++) {
        int cc = wn*96 + ni*16 + c15;
        float hv = (vals[ni][rr] - mu)*rs*cg[ni] + cb2[ni];
        int chunk = cc >> 5, kk2 = cc & 31;
        int pos = ((kk2 >> 3) ^ s_)*8 + (kk2 & 7);
        rowbuf[chunk*1024 + lr*32 + pos] = (f16)hv;
      }
    }
  }
  __syncthreads();            // [4] h2 published

  // ================= phase b: mid = relu(h2 @ W1 + b1) =================
#pragma unroll
  for (int ni = 0; ni < 6; ni++)
    acc[ni] = floatx4{0.f, 0.f, 0.f, 0.f};
  T_GEMM(W1R);
  __syncthreads();            // [5] all h2 reads done before rowbuf overwrite
  {
    float colb[6];
#pragma unroll
    for (int ni = 0; ni < 6; ni++) colb[ni] = b1[wn*96 + ni*16 + c15];
#pragma unroll
    for (int rr = 0; rr < 4; rr++) {
      int lr = wm*16 + q*4 + rr;
      int s_ = (lr >> 1) & 3;
#pragma unroll
      for (int ni = 0; ni < 6; ni++) {
        int cc = wn*96 + ni*16 + c15;
        float v = acc[ni][rr] + colb[ni];
        v = v > 0.f ? v : 0.f;
        int chunk = cc >> 5, kk2 = cc & 31;
        int pos = ((kk2 >> 3) ^ s_)*8 + (kk2 & 7);
        rowbuf[chunk*1024 + lr*32 + pos] = (f16)v;
      }
    }
  }
  __syncthreads();            // [6] mid published

  // ================= phase c: out = x2 + mid @ W2 + b2 =================
#pragma unroll
  for (int ni = 0; ni < 6; ni++)
    acc[ni] = floatx4{0.f, 0.f, 0.f, 0.f};
  T_GEMM(W2R);
  {
    float colb[6];
#pragma unroll
    for (int ni = 0; ni < 6; ni++) colb[ni] = b2[wn*96 + ni*16 + c15];
#pragma unroll
    for (int rr = 0; rr < 4; rr++) {
      long row = row0 + wm*16 + q*4 + rr;
#pragma unroll
      for (int ni = 0; ni < 6; ni++) {
        int col = wn*96 + ni*16 + c15;
        out[row*384 + col] = acc[ni][rr] + colb[ni] + vals[ni][rr];
      }
    }
  }
#undef T_GEMM
}

extern "C" void kernel_launch(void* const* d_in, const int* in_sizes, int n_in,
                              void* d_out, int out_size, void* d_ws, size_t ws_size,
                              hipStream_t stream) {
  const float* x   = (const float*)d_in[0];
  const float* Wq  = (const float*)d_in[1];
  const float* bq  = (const float*)d_in[2];
  const float* Wk  = (const float*)d_in[3];
  const float* bk  = (const float*)d_in[4];
  const float* Wv  = (const float*)d_in[5];
  const float* bv  = (const float*)d_in[6];
  const float* Wp  = (const float*)d_in[7];
  const float* bp  = (const float*)d_in[8];
  const float* W1  = (const float*)d_in[9];
  const float* b1  = (const float*)d_in[10];
  const float* W2  = (const float*)d_in[11];
  const float* b2  = (const float*)d_in[12];
  const float* g1  = (const float*)d_in[13];
  const float* be1 = (const float*)d_in[14];
  const float* g2  = (const float*)d_in[15];
  const float* be2 = (const float*)d_in[16];

  char* ws = (char*)d_ws;
  size_t off = 0;
  auto alloc = [&](size_t bytes) -> void* {
    void* p = ws + off;
    off += (bytes + 255) & ~(size_t)255;
    return p;
  };
  f16*   Wqkv_t = (f16*)  alloc(1152*384*sizeof(f16));  // fragment-major [12][72][512]
  f16*   Wp_t   = (f16*)  alloc(384*384*sizeof(f16));   // fragment-major [12][24][512]
  f16*   W1_t   = (f16*)  alloc(384*384*sizeof(f16));   // fragment-major
  f16*   W2_t   = (f16*)  alloc(384*384*sizeof(f16));   // fragment-major
  float* bqkv   = (float*)alloc(1152*sizeof(float));
  f16*   qkv    = (f16*)  alloc((size_t)NROWS*1152*sizeof(f16));
  f16*   attnb  = (f16*)  alloc((size_t)NROWS*384*sizeof(f16));

  // 1. weight repack (fragment-major) + bias concat -- 217 blocks
  prep_kernel<<<217, 256, 0, stream>>>(Wq, Wk, Wv, bq, bk, bv, Wp, W1, W2,
                                       Wqkv_t, Wp_t, W1_t, W2_t, bqkv);
  // 2. fused LN1 + QKV GEMM: grid (256 row-groups, 2 col-halves)
  qkv_ln_kernel<<<dim3(NROWS/64, 2), 512, 0, stream>>>(x, g1, be1, Wqkv_t, bqkv, qkv);
  // 3. attention: 768 blocks x 512 threads (2 q-tiles per block)
  attn_kernel<<<B_*H_*2, 512, 0, stream>>>(qkv, attnb);
  // 4. fused tail: 32-row blocks, 2 blocks/CU, pipelined B-stream
  tail_kernel<<<NROWS/32, 512, 0, stream>>>(attnb, Wp_t, W1_t, W2_t, bp, b1, b2,
                                            x, g2, be2, (float*)d_out);
}

// Round 14
// 181.117 us; speedup vs baseline: 1.0467x; 1.0467x over previous
//
#include <hip/hip_runtime.h>

typedef _Float16 f16;
typedef _Float16 half8 __attribute__((ext_vector_type(8)));
typedef _Float16 half4v __attribute__((ext_vector_type(4)));
typedef float floatx4 __attribute__((ext_vector_type(4)));

#define B_ 64
#define T_ 256
#define C_ 384
#define H_ 6
#define D_ 64
#define NROWS (B_*T_)

typedef __attribute__((address_space(3))) void lds_void_t;
typedef const __attribute__((address_space(1))) void gvoid_t;

__device__ __forceinline__ void g2lds16(const void* g, void* l) {
  __builtin_amdgcn_global_load_lds((gvoid_t*)g, (lds_void_t*)l, 16, 0, 0);
}

// ---------------- prep: weight repack fp32->f16 FRAGMENT-MAJOR + biases ----------------
// R10-proven:
//   element (col, k) -> W[((k>>5)*NCT + (col>>4))*512 + (((k>>3)&3)*16 + (col&15))*8 + (k&7)]
// Wqkv: NCT=72 (col = mat*384 + h*64 + d); Wp/W1/W2: NCT=24.
__global__ __launch_bounds__(256) void prep_kernel(
    const float* __restrict__ Wq, const float* __restrict__ Wk, const float* __restrict__ Wv,
    const float* __restrict__ bq, const float* __restrict__ bk, const float* __restrict__ bv,
    const float* __restrict__ Wp, const float* __restrict__ W1, const float* __restrict__ W2,
    f16* __restrict__ Wqkv_t, f16* __restrict__ Wp_t, f16* __restrict__ W1_t, f16* __restrict__ W2_t,
    float* __restrict__ bqkv)
{
  const int bid = blockIdx.x;
  const int tid = threadIdx.x;
  if (bid == 216) {
    for (int i = tid; i < 1152; i += 256) {
      float v;
      if (i < 384)      v = bq[i];
      else if (i < 768) v = bk[i - 384];
      else              v = bv[i - 768];
      bqkv[i] = v;
    }
    return;
  }
  __shared__ __align__(16) float tile[64*68];
  const float* src; int srcStride; f16* O; int ctile_base, nct, ks_base;
  if (bid < 108) {
    int mat = bid / 36, rem = bid - mat*36;
    int h = rem / 6, kt = rem - h*6;
    const float* W = (mat == 0) ? Wq : (mat == 1) ? Wk : Wv;
    src = W + (size_t)(h*384 + kt*64)*64;   // rows k (64), cols d (64)
    srcStride = 64;
    O = Wqkv_t; ctile_base = mat*24 + h*4; nct = 72; ks_base = kt*2;
  } else {
    int b2 = bid - 108;
    int mat = b2 / 36, rem = b2 - mat*36;
    int kt = rem / 6, ct = rem - kt*6;
    const float* W = (mat == 0) ? Wp : (mat == 1) ? W1 : W2;
    src = W + (size_t)(kt*64)*384 + ct*64;  // rows k (64), cols d (64)
    srcStride = 384;
    O = (mat == 0) ? Wp_t : (mat == 1) ? W1_t : W2_t;
    ctile_base = ct*4; nct = 24; ks_base = kt*2;
  }
#pragma unroll
  for (int i = 0; i < 4; i++) {
    int idx = i*256 + tid;
    int r = idx >> 4, c4 = idx & 15;
    float4 v = *(const float4*)(src + (size_t)r*srcStride + c4*4);
    *(float4*)(&tile[r*68 + c4*4]) = v;
  }
  __syncthreads();
#pragma unroll
  for (int i = 0; i < 4; i++) {
    int idx = i*256 + tid;
    int d = idx >> 4, k4 = idx & 15;     // d: col within tile; k = k4*4+j
    half4v o;
#pragma unroll
    for (int j = 0; j < 4; j++) o[j] = (f16)tile[(k4*4 + j)*68 + d];
    int ks    = ks_base + (k4 >> 3);
    int ctile = ctile_base + (d >> 4);
    int slotq = (k4 >> 1) & 3;
    size_t off = (size_t)(ks*nct + ctile)*512 + (size_t)(slotq*16 + (d & 15))*8 + (k4 & 1)*4;
    *(half4v*)(O + off) = o;
  }
}

// ---------------- fused LN1 + QKV GEMM (R11-proven) ----------------
__global__ __launch_bounds__(512, 2) void qkv_ln_kernel(
    const float* __restrict__ x, const float* __restrict__ gamma, const float* __restrict__ beta,
    const f16* __restrict__ WR, const float* __restrict__ bias, f16* __restrict__ qkv)
{
  __shared__ __align__(16) f16 rowbuf[12*64*32];   // 49152B: h (LN1 output)
  __shared__ float lnred[2][64][4];
  __shared__ float lnmv[2][64];

  const int tid = threadIdx.x;
  const int lane = tid & 63, w = tid >> 6;
  const int wm = w >> 2, wn = w & 3;
  const int q = lane >> 4, c15 = lane & 15;
  const long row0 = (long)blockIdx.x * 64;
  const int chf = blockIdx.y;          // column half: 0 or 1

  // ---- LN1 over x (full 384 input cols; wn indexes INPUT col-quarters)
  float cg[6], cb[6];
#pragma unroll
  for (int ni = 0; ni < 6; ni++) {
    int col = wn*96 + ni*16 + c15;
    cg[ni] = gamma[col]; cb[ni] = beta[col];
  }
  float xv[2][6][4];
#pragma unroll
  for (int mi = 0; mi < 2; mi++)
#pragma unroll
    for (int rr = 0; rr < 4; rr++) {
      long row = row0 + wm*32 + mi*16 + q*4 + rr;
#pragma unroll
      for (int ni = 0; ni < 6; ni++)
        xv[mi][ni][rr] = x[row*384 + wn*96 + ni*16 + c15];
    }
#pragma unroll
  for (int mi = 0; mi < 2; mi++) {
#pragma unroll
    for (int rr = 0; rr < 4; rr++) {
      float s = 0.f, s2 = 0.f;
#pragma unroll
      for (int ni = 0; ni < 6; ni++) { float v = xv[mi][ni][rr]; s += v; s2 += v*v; }
      s  += __shfl_xor(s, 1);  s  += __shfl_xor(s, 2);  s  += __shfl_xor(s, 4);  s  += __shfl_xor(s, 8);
      s2 += __shfl_xor(s2, 1); s2 += __shfl_xor(s2, 2); s2 += __shfl_xor(s2, 4); s2 += __shfl_xor(s2, 8);
      if (c15 == 0) {
        int lr = wm*32 + mi*16 + q*4 + rr;
        lnred[0][lr][wn] = s;
        lnred[1][lr][wn] = s2;
      }
    }
  }
  __syncthreads();
  if (tid < 64) {
    float s = 0.f, s2 = 0.f;
#pragma unroll
    for (int j = 0; j < 4; j++) { s += lnred[0][tid][j]; s2 += lnred[1][tid][j]; }
    float mu = s * (1.f/384.f);
    float var = s2 * (1.f/384.f) - mu*mu;
    lnmv[0][tid] = mu;
    lnmv[1][tid] = rsqrtf(var + 1e-5f);
  }
  __syncthreads();
  // h -> rowbuf (staged-A swizzled layout; R8/R9-proven write/read pair)
#pragma unroll
  for (int mi = 0; mi < 2; mi++) {
#pragma unroll
    for (int rr = 0; rr < 4; rr++) {
      int lr = wm*32 + mi*16 + q*4 + rr;
      float mu = lnmv[0][lr], rs = lnmv[1][lr];
      int s_ = (lr >> 1) & 3;
#pragma unroll
      for (int ni = 0; ni < 6; ni++) {
        int cc = wn*96 + ni*16 + c15;
        float hv = (xv[mi][ni][rr] - mu)*rs*cg[ni] + cb[ni];
        int chunk = cc >> 5, kk2 = cc & 31;
        int pos = ((kk2 >> 3) ^ s_)*8 + (kk2 & 7);
        rowbuf[chunk*2048 + lr*32 + pos] = (f16)hv;
      }
    }
  }
  __syncthreads();   // h published -- last barrier in the kernel

  // ---- barrier-free GEMM: this block's 576-col half (wn indexes OUTPUT cols)
  floatx4 acc[2][9] = {};
#pragma unroll
  for (int kg = 0; kg < 12; kg++) {
    half8 af[2];
#pragma unroll
    for (int mi = 0; mi < 2; mi++) {
      int r = wm*32 + mi*16 + c15;
      int ph = q ^ ((r >> 1) & 3);
      af[mi] = *(const half8*)(&rowbuf[kg*2048 + r*32 + ph*8]);
    }
#pragma unroll
    for (int g3 = 0; g3 < 3; g3++) {
      half8 bf[3];
#pragma unroll
      for (int ni = 0; ni < 3; ni++)
        bf[ni] = *(const half8*)(WR + (size_t)(kg*72 + chf*36 + wn*9 + g3*3 + ni)*512 + lane*8);
#pragma unroll
      for (int mi = 0; mi < 2; mi++)
#pragma unroll
        for (int ni = 0; ni < 3; ni++)
          acc[mi][g3*3 + ni] = __builtin_amdgcn_mfma_f32_16x16x32_f16(af[mi], bf[ni], acc[mi][g3*3 + ni], 0, 0, 0);
    }
  }

  // ---- epilogue: + bias, f16 out
  float bb[9];
#pragma unroll
  for (int ni = 0; ni < 9; ni++) bb[ni] = bias[chf*576 + wn*144 + ni*16 + c15];
#pragma unroll
  for (int mi = 0; mi < 2; mi++) {
#pragma unroll
    for (int rr = 0; rr < 4; rr++) {
      long row = row0 + wm*32 + mi*16 + q*4 + rr;
#pragma unroll
      for (int ni = 0; ni < 9; ni++) {
        long col = chf*576 + wn*144 + ni*16 + c15;
        qkv[row*1152 + col] = (f16)(acc[mi][ni][rr] + bb[ni]);
      }
    }
  }
}

// ---------------- fused causal attention (R6-proven) ----------------
__global__ __launch_bounds__(512, 2) void attn_kernel(const f16* __restrict__ qkv,
                                                      f16* __restrict__ attn_out)
{
  __shared__ __align__(16) char kvbuf[32768];
  __shared__ __align__(16) f16 Pbuf[8][16*64];
  f16* Ks = (f16*)kvbuf;
  unsigned int* vTw = (unsigned int*)kvbuf;
  f16* vT = (f16*)kvbuf;

  const int tid = threadIdx.x;
  const int bid = blockIdx.x;
  const int bh = bid >> 1, qt2 = bid & 1;
  const int b = bh / 6, h = bh - b*6;
  const f16* qp = qkv + (size_t)b*256*1152 + h*64;
  const f16* kp = qp + 384;
  const f16* vp = qp + 768;
  const int lane = tid & 63, w = tid >> 6;
  const int q = lane >> 4, c15 = lane & 15;

  {
    const int iters = (qt2 + 1) * 2;
    for (int i = 0; i < iters; i++) {
      int pc = i*512 + tid;
      int rc = pc >> 3, p = pc & 7;
      int c = p ^ (rc & 7);
      g2lds16(kp + (size_t)rc*1152 + c*8, (char*)kvbuf + (size_t)(i*512 + w*64)*16);
    }
  }

  const int nmax = qt2*8 + w;
  const int trow0 = qt2*128 + w*16;
  const f16* qrow = qp + (size_t)(trow0 + c15)*1152 + q*8;
  half8 aq0 = *(const half8*)(qrow);
  half8 aq1 = *(const half8*)(qrow + 32);

  __syncthreads();

  floatx4 sacc[16];
  __builtin_amdgcn_s_setprio(1);
#pragma unroll
  for (int ni = 0; ni < 16; ni++) {
    if (ni <= nmax) {
      int s = ni*16 + c15;
      const f16* kr = Ks + s*64;
      int p0 = q ^ (s & 7);
      half8 b0 = *(const half8*)(kr + p0*8);
      half8 b1 = *(const half8*)(kr + (p0 ^ 4)*8);
      floatx4 a = {0.f, 0.f, 0.f, 0.f};
      a = __builtin_amdgcn_mfma_f32_16x16x32_f16(aq0, b0, a, 0, 0, 0);
      a = __builtin_amdgcn_mfma_f32_16x16x32_f16(aq1, b1, a, 0, 0, 0);
      sacc[ni] = a;
    }
  }
  __builtin_amdgcn_s_setprio(0);
  __syncthreads();

  half8 va[2], vb[2];
#pragma unroll
  for (int i = 0; i < 2; i++) {
    if (i <= qt2) {
      int idx = i*512 + tid;
      int sp = idx >> 3, part = idx & 7;
      const f16* v0 = vp + (size_t)(2*sp)*1152 + part*8;
      va[i] = *(const half8*)(v0);
      vb[i] = *(const half8*)(v0 + 1152);
    }
  }

  const float scale = 0.051031036307982884f;
  float mx[4] = {-1e30f, -1e30f, -1e30f, -1e30f};
#pragma unroll
  for (int ni = 0; ni < 16; ni++) {
    if (ni < nmax) {
#pragma unroll
      for (int r = 0; r < 4; r++) { float v = sacc[ni][r]*scale; sacc[ni][r] = v; mx[r] = fmaxf(mx[r], v); }
    } else if (ni == nmax) {
#pragma unroll
      for (int r = 0; r < 4; r++) {
        float v = sacc[ni][r]*scale;
        v = (c15 <= q*4 + r) ? v : -1e30f;
        sacc[ni][r] = v; mx[r] = fmaxf(mx[r], v);
      }
    }
  }
#pragma unroll
  for (int r = 0; r < 4; r++) {
    mx[r] = fmaxf(mx[r], __shfl_xor(mx[r], 1));
    mx[r] = fmaxf(mx[r], __shfl_xor(mx[r], 2));
    mx[r] = fmaxf(mx[r], __shfl_xor(mx[r], 4));
    mx[r] = fmaxf(mx[r], __shfl_xor(mx[r], 8));
  }
  float l[4] = {0.f, 0.f, 0.f, 0.f};
#pragma unroll
  for (int ni = 0; ni < 16; ni++) {
    if (ni <= nmax) {
#pragma unroll
      for (int r = 0; r < 4; r++) { float p = __expf(sacc[ni][r] - mx[r]); sacc[ni][r] = p; l[r] += p; }
    }
  }
#pragma unroll
  for (int r = 0; r < 4; r++) {
    l[r] += __shfl_xor(l[r], 1);
    l[r] += __shfl_xor(l[r], 2);
    l[r] += __shfl_xor(l[r], 4);
    l[r] += __shfl_xor(l[r], 8);
  }

#pragma unroll
  for (int i = 0; i < 2; i++) {
    if (i <= qt2) {
      int idx = i*512 + tid;
      int sp = idx >> 3, part = idx & 7;
      int csp = sp >> 2, spw = sp & 3;
#pragma unroll
      for (int j = 0; j < 8; j++) {
        int d = part*8 + j;
        int swz = (d & 15) ^ (d >> 3);
        int p = csp ^ swz;
        union { struct { f16 lo, hi; } s; unsigned int u; } pk;
        pk.s.lo = va[i][j]; pk.s.hi = vb[i][j];
        vTw[d*128 + p*4 + spw] = pk.u;
      }
    }
  }
  __syncthreads();

  f16* Pw = &Pbuf[w][0];
  floatx4 oacc[4] = {};
  const int kend_w = (nmax + 1) * 16;
#pragma unroll
  for (int ch = 0; ch < 4; ch++) {
    if (ch*64 < kend_w) {
#pragma unroll
      for (int nl = 0; nl < 4; nl++) {
        int ni = ch*4 + nl;
        if (ni <= nmax) {
#pragma unroll
          for (int r = 0; r < 4; r++) {
            int row = q*4 + r;
            int colp = nl*16 + c15;
            int php = (colp >> 3) ^ (row & 7);
            Pw[row*64 + php*8 + (colp & 7)] = (f16)sacc[ni][r];
          }
        } else if (ni == nmax + 1) {
#pragma unroll
          for (int r = 0; r < 4; r++) {
            int row = q*4 + r;
            int colp = nl*16 + c15;
            int php = (colp >> 3) ^ (row & 7);
            Pw[row*64 + php*8 + (colp & 7)] = (f16)0.f;
          }
        }
      }
      __builtin_amdgcn_s_setprio(1);
#pragma unroll
      for (int kc = 0; kc < 2; kc++) {
        if (ch*64 + kc*32 < kend_w) {
          int pc = (kc*4 + q) ^ (c15 & 7);
          half8 ap = *(const half8*)(Pw + c15*64 + pc*8);
          int sc = ch*8 + kc*4 + q;
#pragma unroll
          for (int nt = 0; nt < 4; nt++) {
            int d = nt*16 + c15;
            int swz = (d & 15) ^ (d >> 3);
            half8 bv = *(const half8*)(vT + d*256 + ((sc ^ swz))*8);
            oacc[nt] = __builtin_amdgcn_mfma_f32_16x16x32_f16(ap, bv, oacc[nt], 0, 0, 0);
          }
        }
      }
      __builtin_amdgcn_s_setprio(0);
    }
  }

  float rl[4];
#pragma unroll
  for (int r = 0; r < 4; r++) rl[r] = 1.0f / l[r];
#pragma unroll
  for (int nt = 0; nt < 4; nt++) {
#pragma unroll
    for (int r = 0; r < 4; r++) {
      int t = trow0 + q*4 + r;
      int d = nt*16 + c15;
      attn_out[(size_t)(b*256 + t)*384 + h*64 + d] = (f16)(oacc[nt][r] * rl[r]);
    }
  }
}

// ---------------- fused tail: proj + residual + LN2 + FF1 + FF2 ----------------
// R14: wave = 64 rows x 48 cols (af[4] x bf[3] -> 12 MFMA per 3 B-loads, 4:1).
// R12/R13 waves (16rx96c) amortized 72KB of L2 B-stream over 16 rows (1:1
// MFMA:load) -> per-CU L2 B-traffic 1.7MB/phase; this shape halves per-wave
// B-traffic (36KB) and quadruples compute per load. 64-row blocks, grid 256,
// rowbuf 48KB (R9-proven swizzle pair; per-wave col ownership is irrelevant
// to the element-wise mapping). 1 block/CU, 8 waves, ~130 VGPR live -> no
// spill under __launch_bounds__(512,2) (256 cap). Zero K-loop barriers.
__global__ __launch_bounds__(512, 2) void tail_kernel(
    const f16* __restrict__ A, const f16* __restrict__ WpR,
    const f16* __restrict__ W1R, const f16* __restrict__ W2R,
    const float* __restrict__ bp, const float* __restrict__ b1, const float* __restrict__ b2,
    const float* __restrict__ x, const float* __restrict__ g2, const float* __restrict__ be2,
    float* __restrict__ out)
{
  __shared__ __align__(16) f16 rowbuf[12*64*32];   // 49152B: A / h2 / mid
  __shared__ float lnred[2][64][8];
  __shared__ float lnmv[2][64];

  const int tid = threadIdx.x;
  const int lane = tid & 63, w = tid >> 6;     // wave w owns cols [w*48, w*48+48)
  const int q = lane >> 4, c15 = lane & 15;
  const long row0 = (long)blockIdx.x * 64;

  // A-full staging offsets (16B chunks; XOR-swizzled k-groups) [R9-proven]
  long offA[6];
#pragma unroll
  for (int i = 0; i < 6; i++) {
    int cb = i*512 + tid;
    int kc = cb >> 8, c2 = cb & 255;
    int rA = c2 >> 2, pA = c2 & 3, gA = pA ^ ((rA >> 1) & 3);
    offA[i] = (row0 + rA)*384 + kc*32 + gA*8;
  }

  floatx4 acc[4][3] = {};

  // barrier-free GEMM over full K (12 x 32): A from rowbuf (64 rows),
  // B from L2 (3 ctiles per wave). 12 MFMA per kg.
#define T_GEMM(WR) do { \
    _Pragma("unroll") \
    for (int kg = 0; kg < 12; kg++) { \
      half8 af[4]; \
      _Pragma("unroll") \
      for (int mi = 0; mi < 4; mi++) { \
        int r = mi*16 + c15; \
        int ph = q ^ ((r >> 1) & 3); \
        af[mi] = *(const half8*)(&rowbuf[kg*2048 + r*32 + ph*8]); \
      } \
      half8 bf[3]; \
      _Pragma("unroll") \
      for (int ni = 0; ni < 3; ni++) \
        bf[ni] = *(const half8*)((WR) + (size_t)(kg*24 + w*3 + ni)*512 + (size_t)lane*8); \
      _Pragma("unroll") \
      for (int mi = 0; mi < 4; mi++) \
        _Pragma("unroll") \
        for (int ni = 0; ni < 3; ni++) \
          acc[mi][ni] = __builtin_amdgcn_mfma_f32_16x16x32_f16(af[mi], bf[ni], acc[mi][ni], 0, 0, 0); \
    } \
  } while (0)

  // ---- stage A + prefetch x residual (latency hides under phase a) ----
#pragma unroll
  for (int i = 0; i < 6; i++)
    g2lds16(A + offA[i], (char*)rowbuf + (size_t)(i*512 + w*64)*16);
  float xv[4][3][4];
#pragma unroll
  for (int mi = 0; mi < 4; mi++)
#pragma unroll
    for (int rr = 0; rr < 4; rr++) {
      long row = row0 + mi*16 + q*4 + rr;
#pragma unroll
      for (int ni = 0; ni < 3; ni++)
        xv[mi][ni][rr] = x[row*384 + w*48 + ni*16 + c15];
    }
  __syncthreads();            // [1] A staged

  // ================= phase a: x2 = x + A@Wp + bp ; h2 = LN2(x2) =================
  T_GEMM(WpR);

  float vals[4][3][4];
  {
    float colb[3], cg[3], cb2[3];
#pragma unroll
    for (int ni = 0; ni < 3; ni++) {
      int col = w*48 + ni*16 + c15;
      colb[ni] = bp[col]; cg[ni] = g2[col]; cb2[ni] = be2[col];
    }
#pragma unroll
    for (int mi = 0; mi < 4; mi++)
#pragma unroll
      for (int rr = 0; rr < 4; rr++)
#pragma unroll
        for (int ni = 0; ni < 3; ni++)
          vals[mi][ni][rr] = acc[mi][ni][rr] + colb[ni] + xv[mi][ni][rr];
    // per-row partial sums over this wave's 48 cols
#pragma unroll
    for (int mi = 0; mi < 4; mi++) {
#pragma unroll
      for (int rr = 0; rr < 4; rr++) {
        float s = 0.f, s2 = 0.f;
#pragma unroll
        for (int ni = 0; ni < 3; ni++) { float v = vals[mi][ni][rr]; s += v; s2 += v*v; }
        s  += __shfl_xor(s, 1);  s  += __shfl_xor(s, 2);  s  += __shfl_xor(s, 4);  s  += __shfl_xor(s, 8);
        s2 += __shfl_xor(s2, 1); s2 += __shfl_xor(s2, 2); s2 += __shfl_xor(s2, 4); s2 += __shfl_xor(s2, 8);
        if (c15 == 0) {
          int lr = mi*16 + q*4 + rr;
          lnred[0][lr][w] = s;
          lnred[1][lr][w] = s2;
        }
      }
    }
    __syncthreads();          // [2] lnred ready; all phase-a rowbuf reads done
    if (tid < 64) {
      float s = 0.f, s2 = 0.f;
#pragma unroll
      for (int j = 0; j < 8; j++) { s += lnred[0][tid][j]; s2 += lnred[1][tid][j]; }
      float mu = s * (1.f/384.f);
      float var = s2 * (1.f/384.f) - mu*mu;
      lnmv[0][tid] = mu;
      lnmv[1][tid] = rsqrtf(var + 1e-5f);
    }
    __syncthreads();          // [3] lnmv ready
    // normalize -> h2 into rowbuf (staged-A swizzled layout)
#pragma unroll
    for (int mi = 0; mi < 4; mi++) {
#pragma unroll
      for (int rr = 0; rr < 4; rr++) {
        int lr = mi*16 + q*4 + rr;
        float mu = lnmv[0][lr], rs = lnmv[1][lr];
        int s_ = (lr >> 1) & 3;
#pragma unroll
        for (int ni = 0; ni < 3; ni++) {
          int cc = w*48 + ni*16 + c15;
          float hv = (vals[mi][ni][rr] - mu)*rs*cg[ni] + cb2[ni];
          int chunk = cc >> 5, kk2 = cc & 31;
          int pos = ((kk2 >> 3) ^ s_)*8 + (kk2 & 7);
          rowbuf[chunk*2048 + lr*32 + pos] = (f16)hv;
        }
      }
    }
  }
  __syncthreads();            // [4] h2 published

  // ================= phase b: mid = relu(h2 @ W1 + b1) =================
#pragma unroll
  for (int mi = 0; mi < 4; mi++)
#pragma unroll
    for (int ni = 0; ni < 3; ni++)
      acc[mi][ni] = floatx4{0.f, 0.f, 0.f, 0.f};
  T_GEMM(W1R);
  __syncthreads();            // [5] all h2 reads done before rowbuf overwrite
  {
    float colb[3];
#pragma unroll
    for (int ni = 0; ni < 3; ni++) colb[ni] = b1[w*48 + ni*16 + c15];
#pragma unroll
    for (int mi = 0; mi < 4; mi++) {
#pragma unroll
      for (int rr = 0; rr < 4; rr++) {
        int lr = mi*16 + q*4 + rr;
        int s_ = (lr >> 1) & 3;
#pragma unroll
        for (int ni = 0; ni < 3; ni++) {
          int cc = w*48 + ni*16 + c15;
          float v = acc[mi][ni][rr] + colb[ni];
          v = v > 0.f ? v : 0.f;
          int chunk = cc >> 5, kk2 = cc & 31;
          int pos = ((kk2 >> 3) ^ s_)*8 + (kk2 & 7);
          rowbuf[chunk*2048 + lr*32 + pos] = (f16)v;
        }
      }
    }
  }
  __syncthreads();            // [6] mid published

  // ================= phase c: out = x2 + mid @ W2 + b2 =================
#pragma unroll
  for (int mi = 0; mi < 4; mi++)
#pragma unroll
    for (int ni = 0; ni < 3; ni++)
      acc[mi][ni] = floatx4{0.f, 0.f, 0.f, 0.f};
  T_GEMM(W2R);
  {
    float colb[3];
#pragma unroll
    for (int ni = 0; ni < 3; ni++) colb[ni] = b2[w*48 + ni*16 + c15];
#pragma unroll
    for (int mi = 0; mi < 4; mi++) {
#pragma unroll
      for (int rr = 0; rr < 4; rr++) {
        long row = row0 + mi*16 + q*4 + rr;
#pragma unroll
        for (int ni = 0; ni < 3; ni++) {
          int col = w*48 + ni*16 + c15;
          out[row*384 + col] = acc[mi][ni][rr] + colb[ni] + vals[mi][ni][rr];
        }
      }
    }
  }
#undef T_GEMM
}

extern "C" void kernel_launch(void* const* d_in, const int* in_sizes, int n_in,
                              void* d_out, int out_size, void* d_ws, size_t ws_size,
                              hipStream_t stream) {
  const float* x   = (const float*)d_in[0];
  const float* Wq  = (const float*)d_in[1];
  const float* bq  = (const float*)d_in[2];
  const float* Wk  = (const float*)d_in[3];
  const float* bk  = (const float*)d_in[4];
  const float* Wv  = (const float*)d_in[5];
  const float* bv  = (const float*)d_in[6];
  const float* Wp  = (const float*)d_in[7];
  const float* bp  = (const float*)d_in[8];
  const float* W1  = (const float*)d_in[9];
  const float* b1  = (const float*)d_in[10];
  const float* W2  = (const float*)d_in[11];
  const float* b2  = (const float*)d_in[12];
  const float* g1  = (const float*)d_in[13];
  const float* be1 = (const float*)d_in[14];
  const float* g2  = (const float*)d_in[15];
  const float* be2 = (const float*)d_in[16];

  char* ws = (char*)d_ws;
  size_t off = 0;
  auto alloc = [&](size_t bytes) -> void* {
    void* p = ws + off;
    off += (bytes + 255) & ~(size_t)255;
    return p;
  };
  f16*   Wqkv_t = (f16*)  alloc(1152*384*sizeof(f16));  // fragment-major [12][72][512]
  f16*   Wp_t   = (f16*)  alloc(384*384*sizeof(f16));   // fragment-major [12][24][512]
  f16*   W1_t   = (f16*)  alloc(384*384*sizeof(f16));   // fragment-major
  f16*   W2_t   = (f16*)  alloc(384*384*sizeof(f16));   // fragment-major
  float* bqkv   = (float*)alloc(1152*sizeof(float));
  f16*   qkv    = (f16*)  alloc((size_t)NROWS*1152*sizeof(f16));
  f16*   attnb  = (f16*)  alloc((size_t)NROWS*384*sizeof(f16));

  // 1. weight repack (fragment-major) + bias concat -- 217 blocks
  prep_kernel<<<217, 256, 0, stream>>>(Wq, Wk, Wv, bq, bk, bv, Wp, W1, W2,
                                       Wqkv_t, Wp_t, W1_t, W2_t, bqkv);
  // 2. fused LN1 + QKV GEMM: grid (256 row-groups, 2 col-halves)
  qkv_ln_kernel<<<dim3(NROWS/64, 2), 512, 0, stream>>>(x, g1, be1, Wqkv_t, bqkv, qkv);
  // 3. attention: 768 blocks x 512 threads (2 q-tiles per block)
  attn_kernel<<<B_*H_*2, 512, 0, stream>>>(qkv, attnb);
  // 4. fused tail: 64-row blocks, wave = 64r x 48c (4:1 MFMA:B-load)
  tail_kernel<<<NROWS/64, 512, 0, stream>>>(attnb, Wp_t, W1_t, W2_t, bp, b1, b2,
                                            x, g2, be2, (float*)d_out);
}